// Round 17
// baseline (206.477 us; speedup 1.0000x reference)
//
#include <hip/hip_runtime.h>

#define N_NODES 100000
#define NBIN_D  196           // dst bins of 512 nodes (196*512 = 100352)
#define NW      4             // src windows of 25000 nodes (uniform)
#define WSPAN   25000
#define NBINS_TOT (NW * NBIN_D)   // 784 sort bins, w-major
#define NCHUNK  256
#define CAP     12032         // dlsort LDS stage (mean bin = 8163, +43 sigma)
#define CHUNK_CAP 26624       // scatter1 LDS stage (chunk = 25000 edges)

// ---------------- dtype detection (int64 vs int32 edge_index) ---------------
__global__ void detect_i64_kernel(const unsigned int* __restrict__ e,
                                  unsigned int* __restrict__ flag) {
    int i = blockIdx.x * blockDim.x + threadIdx.x;  // 0..2047
    unsigned int v = e[2 * i + 1];
    if (v != 0u) atomicOr(flag, 1u);
}

// ---------------- pad x (N x 5 f32) -> fp32x8 (32B rows) --------------------
__global__ void pad_x_kernel(const float* __restrict__ x, float4* __restrict__ xp, int N) {
    int n = blockIdx.x * blockDim.x + threadIdx.x;
    if (n >= N) return;
    const float* p = x + (long long)n * 5;
    xp[n * 2]     = make_float4(p[0], p[1], p[2], p[3]);
    xp[n * 2 + 1] = make_float4(p[4], 0.f, 0.f, 0.f);
}

// ------- pass 1a: histogram over (w, dst_bin) + emit compact key stream -----
// keys[e] = (dl<<17)|src, bins[e] = sort-bin index (w*NBIN_D + dbin)
__global__ __launch_bounds__(1024) void count_kernel(
    const void* __restrict__ eidx, const unsigned int* __restrict__ flag,
    int* __restrict__ hist, unsigned int* __restrict__ keys,
    unsigned short* __restrict__ bins, int E) {
    __shared__ int lh[NBINS_TOT];
    int tid = threadIdx.x, c = blockIdx.x;
    for (int i = tid; i < NBINS_TOT; i += 1024) lh[i] = 0;
    __syncthreads();
    int per = (E + NCHUNK - 1) / NCHUNK;
    int e0 = c * per, e1 = min(E, e0 + per);
    unsigned int is32 = *flag;
    for (int e = e0 + tid; e < e1; e += 1024) {
        int s, d;
        if (is32) {
            const int* p = (const int*)eidx; s = p[e]; d = p[E + e];
        } else {
            const long long* p = (const long long*)eidx; s = (int)p[e]; d = (int)p[E + e];
        }
        int b = (s / WSPAN) * NBIN_D + (d >> 9);
        keys[e] = ((unsigned int)(d & 511) << 17) | (unsigned int)s;
        bins[e] = (unsigned short)b;
        atomicAdd(&lh[b], 1);
    }
    __syncthreads();
    for (int i = tid; i < NBINS_TOT; i += 1024) hist[c * NBINS_TOT + i] = lh[i];
}

// ---------------- pass 1b: per-bin column scan (1 wave per bin) -------------
__global__ void scan1_kernel(const int* __restrict__ hist,
                             int* __restrict__ off_rel,
                             int* __restrict__ totals) {
    int gtid = blockIdx.x * blockDim.x + threadIdx.x;
    int b = gtid >> 6;
    int lane = threadIdx.x & 63;
    if (b >= NBINS_TOT) return;
    int carry = 0;
    for (int k = 0; k < NCHUNK; k += 64) {
        int v = hist[(k + lane) * NBINS_TOT + b];
        int sc = v;
        for (int off = 1; off < 64; off <<= 1) {
            int t = __shfl_up(sc, off);
            if (lane >= off) sc += t;
        }
        off_rel[(k + lane) * NBINS_TOT + b] = carry + sc - v;   // exclusive
        carry += __shfl(sc, 63);
    }
    if (lane == 0) totals[b] = carry;
}

// ---------------- pass 1c: scan bin totals -> bin_start ---------------------
__global__ void scan2_kernel(const int* __restrict__ totals,
                             int* __restrict__ bin_start) {
    __shared__ int buf[1024];
    int tid = threadIdx.x;
    buf[tid] = (tid < NBINS_TOT) ? totals[tid] : 0;
    __syncthreads();
    for (int off = 1; off < 1024; off <<= 1) {
        int v = (tid >= off) ? buf[tid - off] : 0;
        __syncthreads();
        buf[tid] += v;
        __syncthreads();
    }
    if (tid < NBINS_TOT) bin_start[tid + 1] = buf[tid];
    if (tid == 0) bin_start[0] = 0;
}

// ------- pass 1d: LDS counting sort per chunk -> coalesced global writes ----
__global__ __launch_bounds__(1024) void scatter1_staged(
    const unsigned int* __restrict__ keys, const unsigned short* __restrict__ bins,
    const int* __restrict__ hist, const int* __restrict__ off_rel,
    const int* __restrict__ bin_start,
    unsigned int* __restrict__ sorted1, int E) {
    __shared__ unsigned int staged[CHUNK_CAP];
    __shared__ int lstart[NBINS_TOT];
    __shared__ int lcur[NBINS_TOT];
    __shared__ int scanbuf[1024];
    int tid = threadIdx.x, c = blockIdx.x;
    int v = (tid < NBINS_TOT) ? hist[c * NBINS_TOT + tid] : 0;
    scanbuf[tid] = v;
    __syncthreads();
    for (int off = 1; off < 1024; off <<= 1) {
        int t = (tid >= off) ? scanbuf[tid - off] : 0;
        __syncthreads();
        scanbuf[tid] += t;
        __syncthreads();
    }
    if (tid < NBINS_TOT) {
        int excl = scanbuf[tid] - v;
        lstart[tid] = excl;
        lcur[tid] = excl;
    }
    __syncthreads();
    int per = (E + NCHUNK - 1) / NCHUNK;
    int e0 = c * per, e1 = min(E, e0 + per);
    for (int e = e0 + tid; e < e1; e += 1024) {
        unsigned int k = keys[e];
        int b = bins[e];
        int pos = atomicAdd(&lcur[b], 1);
        staged[pos] = k;
    }
    __syncthreads();
    int wv = tid >> 6, lane = tid & 63;
    for (int b = wv; b < NBINS_TOT; b += 16) {
        int ls = lstart[b];
        int cnt = lcur[b] - ls;
        int gd = bin_start[b] + off_rel[c * NBINS_TOT + b];
        for (int i = lane; i < cnt; i += 64)
            sorted1[gd + i] = staged[ls + i];
    }
}

// ---- fallback scatter (per > CHUNK_CAP): scattered stores, always correct --
__global__ __launch_bounds__(1024) void scatter1_kernel(
    const unsigned int* __restrict__ keys, const unsigned short* __restrict__ bins,
    const int* __restrict__ off_rel, const int* __restrict__ bin_start,
    unsigned int* __restrict__ sorted1, int E) {
    __shared__ int lcnt[NBINS_TOT];
    __shared__ int lbase[NBINS_TOT];
    int tid = threadIdx.x, c = blockIdx.x;
    for (int i = tid; i < NBINS_TOT; i += 1024) {
        lcnt[i] = 0;
        lbase[i] = bin_start[i] + off_rel[c * NBINS_TOT + i];
    }
    __syncthreads();
    int per = (E + NCHUNK - 1) / NCHUNK;
    int e0 = c * per, e1 = min(E, e0 + per);
    for (int e = e0 + tid; e < e1; e += 1024) {
        unsigned int k = keys[e];
        int b = bins[e];
        int pos = lbase[b] + atomicAdd(&lcnt[b], 1);
        sorted1[pos] = k;
    }
}

// ---------------- pass 2: per-(w,bin) LDS counting sort -> window CSR -------
__global__ __launch_bounds__(512) void dlsort_kernel(
    const unsigned int* __restrict__ sorted1,
    const int* __restrict__ bin_start,
    unsigned int* __restrict__ sorted2,
    int* __restrict__ rp, int N) {
    __shared__ int hist[512];
    __shared__ int pfx[512];
    __shared__ int offc[512];
    __shared__ unsigned int stage[CAP];
    int tid = threadIdx.x, b = blockIdx.x;
    int w = b / NBIN_D, dbin = b - w * NBIN_D;
    int bs = bin_start[b], be = bin_start[b + 1];
    int cnt = be - bs;
    hist[tid] = 0;
    __syncthreads();
    for (int e = bs + tid; e < be; e += 512)
        atomicAdd(&hist[(sorted1[e] >> 17) & 511], 1);
    __syncthreads();
    pfx[tid] = hist[tid];
    __syncthreads();
    for (int off = 1; off < 512; off <<= 1) {
        int v = (tid >= off) ? pfx[tid - off] : 0;
        __syncthreads();
        pfx[tid] += v;
        __syncthreads();
    }
    {
        int excl = pfx[tid] - hist[tid];
        offc[tid] = excl;
        int node = dbin * 512 + tid;
        if (node <= N) rp[w * (N + 1) + node] = bs + excl;
    }
    __syncthreads();
    if (cnt <= CAP) {
        for (int e = bs + tid; e < be; e += 512) {
            unsigned int wd = sorted1[e];
            int pos = atomicAdd(&offc[(wd >> 17) & 511], 1);
            stage[pos] = wd;
        }
        __syncthreads();
        for (int i = tid; i < cnt; i += 512) sorted2[bs + i] = stage[i];
    } else {
        for (int e = bs + tid; e < be; e += 512) {
            unsigned int wd = sorted1[e];
            int pos = bs + atomicAdd(&offc[(wd >> 17) & 511], 1);
            sorted2[pos] = wd;
        }
    }
}

// -- aggregation F=5 (layer 1): 4 lanes/node, window-PAIR dual streams -------
__global__ __launch_bounds__(256) void agg5_csr(
    const unsigned int* __restrict__ sorted2, const int* __restrict__ rp,
    const float4* __restrict__ xp, float* __restrict__ agg, int N) {
    int t = blockIdx.x * 256 + threadIdx.x;
    int n = t >> 2, p = t & 3;
    if (n >= N) return;
    float a0 = 0, a1 = 0, a2 = 0, a3 = 0, a4 = 0;
#pragma unroll
    for (int wp = 0; wp < NW; wp += 2) {
        int eA  = rp[wp * (N + 1) + n] + p,       eA1 = rp[wp * (N + 1) + n + 1];
        int eB  = rp[(wp + 1) * (N + 1) + n] + p, eB1 = rp[(wp + 1) * (N + 1) + n + 1];
        while (eA < eA1 && eB < eB1) {
            int sA = (int)(sorted2[eA] & 0x1FFFF);
            int sB = (int)(sorted2[eB] & 0x1FFFF);
            float4 vA = xp[sA * 2], wA = xp[sA * 2 + 1];
            float4 vB = xp[sB * 2], wB = xp[sB * 2 + 1];
            a0 += vA.x; a1 += vA.y; a2 += vA.z; a3 += vA.w; a4 += wA.x;
            a0 += vB.x; a1 += vB.y; a2 += vB.z; a3 += vB.w; a4 += wB.x;
            eA += 4; eB += 4;
        }
        while (eA < eA1) {
            int sA = (int)(sorted2[eA] & 0x1FFFF);
            float4 vA = xp[sA * 2], wA = xp[sA * 2 + 1];
            a0 += vA.x; a1 += vA.y; a2 += vA.z; a3 += vA.w; a4 += wA.x;
            eA += 4;
        }
        while (eB < eB1) {
            int sB = (int)(sorted2[eB] & 0x1FFFF);
            float4 vB = xp[sB * 2], wB = xp[sB * 2 + 1];
            a0 += vB.x; a1 += vB.y; a2 += vB.z; a3 += vB.w; a4 += wB.x;
            eB += 4;
        }
    }
    // combine the four edge-split lanes
    a0 += __shfl_xor(a0, 1); a1 += __shfl_xor(a1, 1); a2 += __shfl_xor(a2, 1);
    a3 += __shfl_xor(a3, 1); a4 += __shfl_xor(a4, 1);
    a0 += __shfl_xor(a0, 2); a1 += __shfl_xor(a1, 2); a2 += __shfl_xor(a2, 2);
    a3 += __shfl_xor(a3, 2); a4 += __shfl_xor(a4, 2);
    if (p == 0) {
        float* o = agg + (long long)n * 5;
        o[0] = a0; o[1] = a1; o[2] = a2; o[3] = a3; o[4] = a4;
    }
}

// -- aggregation F=16 (layer 2): 8 lanes/node, window-PAIR dual streams ------
// q = feature quad (contiguous 64B line across q=0..3), p = edge parity.
// Window pair (3.2MB < 4MB XCD L2) gives two independent gather chains.
__global__ __launch_bounds__(256) void agg16_csr(
    const unsigned int* __restrict__ sorted2, const int* __restrict__ rp,
    const float4* __restrict__ h, float* __restrict__ agg, int N) {
    int t = blockIdx.x * 256 + threadIdx.x;
    int n = t >> 3, l = t & 7;
    int q = l & 3, p = l >> 2;
    if (n >= N) return;
    float a0 = 0, a1 = 0, a2 = 0, a3 = 0;
#pragma unroll
    for (int wp = 0; wp < NW; wp += 2) {
        int eA  = rp[wp * (N + 1) + n] + p,       eA1 = rp[wp * (N + 1) + n + 1];
        int eB  = rp[(wp + 1) * (N + 1) + n] + p, eB1 = rp[(wp + 1) * (N + 1) + n + 1];
        // dual-stream main loop: 4 independent gathers in flight
        while (eA + 2 < eA1 && eB + 2 < eB1) {
            int sA0 = (int)(sorted2[eA] & 0x1FFFF);
            int sA1 = (int)(sorted2[eA + 2] & 0x1FFFF);
            int sB0 = (int)(sorted2[eB] & 0x1FFFF);
            int sB1 = (int)(sorted2[eB + 2] & 0x1FFFF);
            float4 vA0 = h[sA0 * 4 + q];
            float4 vA1 = h[sA1 * 4 + q];
            float4 vB0 = h[sB0 * 4 + q];
            float4 vB1 = h[sB1 * 4 + q];
            a0 += vA0.x; a1 += vA0.y; a2 += vA0.z; a3 += vA0.w;
            a0 += vA1.x; a1 += vA1.y; a2 += vA1.z; a3 += vA1.w;
            a0 += vB0.x; a1 += vB0.y; a2 += vB0.z; a3 += vB0.w;
            a0 += vB1.x; a1 += vB1.y; a2 += vB1.z; a3 += vB1.w;
            eA += 4; eB += 4;
        }
        while (eA < eA1) {
            int sA = (int)(sorted2[eA] & 0x1FFFF);
            float4 vA = h[sA * 4 + q];
            a0 += vA.x; a1 += vA.y; a2 += vA.z; a3 += vA.w;
            eA += 2;
        }
        while (eB < eB1) {
            int sB = (int)(sorted2[eB] & 0x1FFFF);
            float4 vB = h[sB * 4 + q];
            a0 += vB.x; a1 += vB.y; a2 += vB.z; a3 += vB.w;
            eB += 2;
        }
    }
    // combine the two edge-parity halves (lane l <-> l^4)
    a0 += __shfl_xor(a0, 4);
    a1 += __shfl_xor(a1, 4);
    a2 += __shfl_xor(a2, 4);
    a3 += __shfl_xor(a3, 4);
    if (p == 0) {
        float4* o = (float4*)(agg + (long long)n * 16);
        o[q] = make_float4(a0, a1, a2, a3);
    }
}

// ------------- MLP1: h = relu((x+agg1)@W1a+b1a)@W1b+b1b  (fp32 h) -----------
__global__ void mlp1_kernel(const float* __restrict__ x,
                            const float* __restrict__ agg,
                            const float* __restrict__ W1, const float* __restrict__ b1,
                            const float* __restrict__ W2, const float* __restrict__ b2,
                            float* __restrict__ h, int N) {
    int n = blockIdx.x * blockDim.x + threadIdx.x;
    if (n >= N) return;
    float in[5];
#pragma unroll
    for (int f = 0; f < 5; ++f)
        in[f] = x[(long long)n * 5 + f] + agg[(long long)n * 5 + f];
    float hid[16];
#pragma unroll
    for (int j = 0; j < 16; ++j) {
        float acc = b1[j];
#pragma unroll
        for (int f = 0; f < 5; ++f) acc = fmaf(in[f], W1[f * 16 + j], acc);
        hid[j] = fmaxf(acc, 0.0f);
    }
    float4* op = (float4*)(h + (long long)n * 16);
#pragma unroll
    for (int jq = 0; jq < 4; ++jq) {
        float4 v;
        float acc;
        acc = b2[jq * 4 + 0];
#pragma unroll
        for (int k = 0; k < 16; ++k) acc = fmaf(hid[k], W2[k * 16 + jq * 4 + 0], acc);
        v.x = acc;
        acc = b2[jq * 4 + 1];
#pragma unroll
        for (int k = 0; k < 16; ++k) acc = fmaf(hid[k], W2[k * 16 + jq * 4 + 1], acc);
        v.y = acc;
        acc = b2[jq * 4 + 2];
#pragma unroll
        for (int k = 0; k < 16; ++k) acc = fmaf(hid[k], W2[k * 16 + jq * 4 + 2], acc);
        v.z = acc;
        acc = b2[jq * 4 + 3];
#pragma unroll
        for (int k = 0; k < 16; ++k) acc = fmaf(hid[k], W2[k * 16 + jq * 4 + 3], acc);
        v.w = acc;
        op[jq] = v;
    }
}

// ------------- MLP2: out = relu((h+agg2)@W2a+b2a)@W2b+b2b -------------------
__global__ void mlp2_kernel(const float* __restrict__ h,
                            const float* __restrict__ agg,
                            const float* __restrict__ W1, const float* __restrict__ b1,
                            const float* __restrict__ W2, const float* __restrict__ b2,
                            float* __restrict__ out, int N) {
    int n = blockIdx.x * blockDim.x + threadIdx.x;
    if (n >= N) return;
    float in[16];
    const float4* hp = (const float4*)(h + (long long)n * 16);
    const float4* ap = (const float4*)(agg + (long long)n * 16);
#pragma unroll
    for (int qq = 0; qq < 4; ++qq) {
        float4 a = hp[qq], b = ap[qq];
        in[qq * 4 + 0] = a.x + b.x; in[qq * 4 + 1] = a.y + b.y;
        in[qq * 4 + 2] = a.z + b.z; in[qq * 4 + 3] = a.w + b.w;
    }
    float hid[16];
#pragma unroll
    for (int j = 0; j < 16; ++j) {
        float acc = b1[j];
#pragma unroll
        for (int f = 0; f < 16; ++f) acc = fmaf(in[f], W1[f * 16 + j], acc);
        hid[j] = fmaxf(acc, 0.0f);
    }
    float4* op = (float4*)(out + (long long)n * 16);
#pragma unroll
    for (int jq = 0; jq < 4; ++jq) {
        float4 v;
        float acc;
        acc = b2[jq * 4 + 0];
#pragma unroll
        for (int k = 0; k < 16; ++k) acc = fmaf(hid[k], W2[k * 16 + jq * 4 + 0], acc);
        v.x = acc;
        acc = b2[jq * 4 + 1];
#pragma unroll
        for (int k = 0; k < 16; ++k) acc = fmaf(hid[k], W2[k * 16 + jq * 4 + 1], acc);
        v.y = acc;
        acc = b2[jq * 4 + 2];
#pragma unroll
        for (int k = 0; k < 16; ++k) acc = fmaf(hid[k], W2[k * 16 + jq * 4 + 2], acc);
        v.z = acc;
        acc = b2[jq * 4 + 3];
#pragma unroll
        for (int k = 0; k < 16; ++k) acc = fmaf(hid[k], W2[k * 16 + jq * 4 + 3], acc);
        v.w = acc;
        op[jq] = v;
    }
}

// ---------- fallback path (ws too small): global atomics, fp32 --------------
__device__ __forceinline__ void load_edge(const void* eidx, unsigned int is32,
                                          int i, int E, int& s, int& d) {
    if (is32 == 0u) {
        const long long* p = (const long long*)eidx;
        s = (int)p[i]; d = (int)p[E + i];
    } else {
        const int* p = (const int*)eidx;
        s = p[i]; d = p[E + i];
    }
}

__global__ void scatter_f5_kernel(const void* __restrict__ eidx,
                                  const unsigned int* __restrict__ flag,
                                  const float* __restrict__ x,
                                  float* __restrict__ agg, int E) {
    int i = blockIdx.x * blockDim.x + threadIdx.x;
    if (i >= E) return;
    int s, d; load_edge(eidx, *flag, i, E, s, d);
    const float* xs = x + (long long)s * 5;
    float* a = agg + (long long)d * 5;
#pragma unroll
    for (int f = 0; f < 5; ++f) atomicAdd(&a[f], xs[f]);
}

__global__ void scatter_f16_kernel(const void* __restrict__ eidx,
                                   const unsigned int* __restrict__ flag,
                                   const float* __restrict__ h,
                                   float* __restrict__ agg, int E) {
    int i = blockIdx.x * blockDim.x + threadIdx.x;
    if (i >= E) return;
    int s, d; load_edge(eidx, *flag, i, E, s, d);
    const float* hs = h + (long long)s * 16;
    float* a = agg + (long long)d * 16;
#pragma unroll
    for (int f = 0; f < 16; ++f) atomicAdd(&a[f], hs[f]);
}

extern "C" void kernel_launch(void* const* d_in, const int* in_sizes, int n_in,
                              void* d_out, int out_size, void* d_ws, size_t ws_size,
                              hipStream_t stream) {
    const float* x    = (const float*)d_in[0];
    const void*  eidx = d_in[1];
    const float* W1a  = (const float*)d_in[2];
    const float* b1a  = (const float*)d_in[3];
    const float* W1b  = (const float*)d_in[4];
    const float* b1b  = (const float*)d_in[5];
    const float* W2a  = (const float*)d_in[6];
    const float* b2a  = (const float*)d_in[7];
    const float* W2b  = (const float*)d_in[8];
    const float* b2b  = (const float*)d_in[9];
    float* out = (float*)d_out;

    const int E = in_sizes[1] / 2;
    const int N = N_NODES;

    char* ws = (char*)d_ws;
    auto align256 = [](size_t v) { return (v + 255) & ~(size_t)255; };
    const size_t hist_bytes = (size_t)NCHUNK * NBINS_TOT * 4;          // 802,816

    const size_t off_flag     = 0;
    const size_t off_binstart = 256;                                    // 785*4
    const size_t off_totals   = align256(off_binstart + (NBINS_TOT + 1) * 4);
    const size_t off_rp       = align256(off_totals + NBINS_TOT * 4);   // NW*(N+1)*4
    const size_t off_hist     = align256(off_rp + (size_t)NW * (N + 1) * 4);
    const size_t off_offrel   = align256(off_hist + hist_bytes);
    const size_t off_xp       = align256(off_offrel + hist_bytes);      // N*32 fp32x8
    const size_t off_sorted1  = align256(off_xp + (size_t)N * 32);      // E*4
    const size_t off_sorted2  = align256(off_sorted1 + (size_t)E * 4);  // E*4 (also keys)
    const size_t off_bins     = align256(off_sorted2 + (size_t)E * 4);  // E*2
    const size_t need         = off_bins + (size_t)E * 2;

    // keys alias the sorted2 slot (keys consumed by scatter1 before dlsort
    // writes sorted2). agg1/agg2/h alias the dead sorted1 region after dlsort:
    //   agg1 @ +0, agg2 @ +2MiB, h @ +9MiB  (15.8 MB < E*4 = 25.6 MB)
    unsigned int* flag = (unsigned int*)(ws + off_flag);

    if (ws_size >= need && (size_t)E * 4 >= 9 * 1024 * 1024 + (size_t)N * 64) {
        int* bin_start        = (int*)(ws + off_binstart);
        int* totals           = (int*)(ws + off_totals);
        int* rp               = (int*)(ws + off_rp);
        int* hist             = (int*)(ws + off_hist);
        int* off_rel          = (int*)(ws + off_offrel);
        float4* xp            = (float4*)(ws + off_xp);
        unsigned int* sorted1 = (unsigned int*)(ws + off_sorted1);
        unsigned int* sorted2 = (unsigned int*)(ws + off_sorted2);
        unsigned int* keys    = (unsigned int*)(ws + off_sorted2);      // alias
        unsigned short* bins  = (unsigned short*)(ws + off_bins);
        float* agg1 = (float*)(ws + off_sorted1);
        float* agg2 = (float*)(ws + off_sorted1 + 2 * 1024 * 1024);
        float* h    = (float*)(ws + off_sorted1 + 9 * 1024 * 1024);

        const int per = (E + NCHUNK - 1) / NCHUNK;

        hipMemsetAsync(ws, 0, 4, stream);
        detect_i64_kernel<<<8, 256, 0, stream>>>((const unsigned int*)eidx, flag);
        pad_x_kernel<<<(N + 255) / 256, 256, 0, stream>>>(x, xp, N);
        count_kernel<<<NCHUNK, 1024, 0, stream>>>(eidx, flag, hist, keys, bins, E);
        scan1_kernel<<<(NBINS_TOT * 64 + 511) / 512, 512, 0, stream>>>(hist, off_rel, totals);
        scan2_kernel<<<1, 1024, 0, stream>>>(totals, bin_start);
        if (per <= CHUNK_CAP) {
            scatter1_staged<<<NCHUNK, 1024, 0, stream>>>(keys, bins, hist, off_rel,
                                                         bin_start, sorted1, E);
        } else {
            scatter1_kernel<<<NCHUNK, 1024, 0, stream>>>(keys, bins, off_rel,
                                                         bin_start, sorted1, E);
        }
        dlsort_kernel<<<NBINS_TOT, 512, 0, stream>>>(sorted1, bin_start, sorted2, rp, N);

        agg5_csr<<<(4 * N + 255) / 256, 256, 0, stream>>>(sorted2, rp, xp, agg1, N);
        mlp1_kernel<<<(N + 255) / 256, 256, 0, stream>>>(x, agg1, W1a, b1a, W1b, b1b, h, N);
        agg16_csr<<<(8 * N + 255) / 256, 256, 0, stream>>>(sorted2, rp, (const float4*)h, agg2, N);
        mlp2_kernel<<<(N + 255) / 256, 256, 0, stream>>>(h, agg2, W2a, b2a, W2b, b2b, out, N);
    } else {
        // fallback: global-atomic path
        const size_t f_agg1 = 4096;
        const size_t f_agg2 = f_agg1 + 2 * 1024 * 1024;
        const size_t f_h    = f_agg2 + 7 * 1024 * 1024;
        float* agg1 = (float*)(ws + f_agg1);
        float* agg2 = (float*)(ws + f_agg2);
        float* h    = (float*)(ws + f_h);

        hipMemsetAsync(ws, 0, f_agg2 + (size_t)N * 16 * 4, stream);
        detect_i64_kernel<<<8, 256, 0, stream>>>((const unsigned int*)eidx, flag);
        int blocks = (E + 255) / 256;
        scatter_f5_kernel<<<blocks, 256, 0, stream>>>(eidx, flag, x, agg1, E);
        mlp1_kernel<<<(N + 255) / 256, 256, 0, stream>>>(x, agg1, W1a, b1a, W1b, b1b, h, N);
        scatter_f16_kernel<<<blocks, 256, 0, stream>>>(eidx, flag, h, agg2, E);
        mlp2_kernel<<<(N + 255) / 256, 256, 0, stream>>>(h, agg2, W2a, b2a, W2b, b2b, out, N);
    }
}

// Round 18
// 196.039 us; speedup vs baseline: 1.0532x; 1.0532x over previous
//
#include <hip/hip_runtime.h>

#define N_NODES 100000
#define NBIN_D  196           // dst bins of 512 nodes (196*512 = 100352)
#define NW      4             // src windows of 25000 nodes (uniform)
#define WSPAN   25000
#define NBINS_TOT (NW * NBIN_D)   // 784 sort bins, w-major
#define NCHUNK  256
#define CAP     12032         // dlsort LDS stage (mean bin = 8163, +43 sigma)
#define CHUNK_CAP 26624       // scatter1 LDS stage (chunk = 25000 edges)

// ---------------- dtype detection (int64 vs int32 edge_index) ---------------
__global__ void detect_i64_kernel(const unsigned int* __restrict__ e,
                                  unsigned int* __restrict__ flag) {
    int i = blockIdx.x * blockDim.x + threadIdx.x;  // 0..2047
    unsigned int v = e[2 * i + 1];
    if (v != 0u) atomicOr(flag, 1u);
}

// ---------------- pad x (N x 5 f32) -> fp32x8 (32B rows) --------------------
__global__ void pad_x_kernel(const float* __restrict__ x, float4* __restrict__ xp, int N) {
    int n = blockIdx.x * blockDim.x + threadIdx.x;
    if (n >= N) return;
    const float* p = x + (long long)n * 5;
    xp[n * 2]     = make_float4(p[0], p[1], p[2], p[3]);
    xp[n * 2 + 1] = make_float4(p[4], 0.f, 0.f, 0.f);
}

// ------- pass 1a: histogram over (w, dst_bin) + emit compact key stream -----
// keys[e] = (dl<<17)|src, bins[e] = sort-bin index (w*NBIN_D + dbin)
__global__ __launch_bounds__(1024) void count_kernel(
    const void* __restrict__ eidx, const unsigned int* __restrict__ flag,
    int* __restrict__ hist, unsigned int* __restrict__ keys,
    unsigned short* __restrict__ bins, int E) {
    __shared__ int lh[NBINS_TOT];
    int tid = threadIdx.x, c = blockIdx.x;
    for (int i = tid; i < NBINS_TOT; i += 1024) lh[i] = 0;
    __syncthreads();
    int per = (E + NCHUNK - 1) / NCHUNK;
    int e0 = c * per, e1 = min(E, e0 + per);
    unsigned int is32 = *flag;
    for (int e = e0 + tid; e < e1; e += 1024) {
        int s, d;
        if (is32) {
            const int* p = (const int*)eidx; s = p[e]; d = p[E + e];
        } else {
            const long long* p = (const long long*)eidx; s = (int)p[e]; d = (int)p[E + e];
        }
        int b = (s / WSPAN) * NBIN_D + (d >> 9);
        keys[e] = ((unsigned int)(d & 511) << 17) | (unsigned int)s;
        bins[e] = (unsigned short)b;
        atomicAdd(&lh[b], 1);
    }
    __syncthreads();
    for (int i = tid; i < NBINS_TOT; i += 1024) hist[c * NBINS_TOT + i] = lh[i];
}

// ---------------- pass 1b: per-bin column scan (1 wave per bin) -------------
__global__ void scan1_kernel(const int* __restrict__ hist,
                             int* __restrict__ off_rel,
                             int* __restrict__ totals) {
    int gtid = blockIdx.x * blockDim.x + threadIdx.x;
    int b = gtid >> 6;
    int lane = threadIdx.x & 63;
    if (b >= NBINS_TOT) return;
    int carry = 0;
    for (int k = 0; k < NCHUNK; k += 64) {
        int v = hist[(k + lane) * NBINS_TOT + b];
        int sc = v;
        for (int off = 1; off < 64; off <<= 1) {
            int t = __shfl_up(sc, off);
            if (lane >= off) sc += t;
        }
        off_rel[(k + lane) * NBINS_TOT + b] = carry + sc - v;   // exclusive
        carry += __shfl(sc, 63);
    }
    if (lane == 0) totals[b] = carry;
}

// ---------------- pass 1c: scan bin totals -> bin_start ---------------------
__global__ void scan2_kernel(const int* __restrict__ totals,
                             int* __restrict__ bin_start) {
    __shared__ int buf[1024];
    int tid = threadIdx.x;
    buf[tid] = (tid < NBINS_TOT) ? totals[tid] : 0;
    __syncthreads();
    for (int off = 1; off < 1024; off <<= 1) {
        int v = (tid >= off) ? buf[tid - off] : 0;
        __syncthreads();
        buf[tid] += v;
        __syncthreads();
    }
    if (tid < NBINS_TOT) bin_start[tid + 1] = buf[tid];
    if (tid == 0) bin_start[0] = 0;
}

// ------- pass 1d: LDS counting sort per chunk -> coalesced global writes ----
__global__ __launch_bounds__(1024) void scatter1_staged(
    const unsigned int* __restrict__ keys, const unsigned short* __restrict__ bins,
    const int* __restrict__ hist, const int* __restrict__ off_rel,
    const int* __restrict__ bin_start,
    unsigned int* __restrict__ sorted1, int E) {
    __shared__ unsigned int staged[CHUNK_CAP];
    __shared__ int lstart[NBINS_TOT];
    __shared__ int lcur[NBINS_TOT];
    __shared__ int scanbuf[1024];
    int tid = threadIdx.x, c = blockIdx.x;
    int v = (tid < NBINS_TOT) ? hist[c * NBINS_TOT + tid] : 0;
    scanbuf[tid] = v;
    __syncthreads();
    for (int off = 1; off < 1024; off <<= 1) {
        int t = (tid >= off) ? scanbuf[tid - off] : 0;
        __syncthreads();
        scanbuf[tid] += t;
        __syncthreads();
    }
    if (tid < NBINS_TOT) {
        int excl = scanbuf[tid] - v;
        lstart[tid] = excl;
        lcur[tid] = excl;
    }
    __syncthreads();
    int per = (E + NCHUNK - 1) / NCHUNK;
    int e0 = c * per, e1 = min(E, e0 + per);
    for (int e = e0 + tid; e < e1; e += 1024) {
        unsigned int k = keys[e];
        int b = bins[e];
        int pos = atomicAdd(&lcur[b], 1);
        staged[pos] = k;
    }
    __syncthreads();
    int wv = tid >> 6, lane = tid & 63;
    for (int b = wv; b < NBINS_TOT; b += 16) {
        int ls = lstart[b];
        int cnt = lcur[b] - ls;
        int gd = bin_start[b] + off_rel[c * NBINS_TOT + b];
        for (int i = lane; i < cnt; i += 64)
            sorted1[gd + i] = staged[ls + i];
    }
}

// ---- fallback scatter (per > CHUNK_CAP): scattered stores, always correct --
__global__ __launch_bounds__(1024) void scatter1_kernel(
    const unsigned int* __restrict__ keys, const unsigned short* __restrict__ bins,
    const int* __restrict__ off_rel, const int* __restrict__ bin_start,
    unsigned int* __restrict__ sorted1, int E) {
    __shared__ int lcnt[NBINS_TOT];
    __shared__ int lbase[NBINS_TOT];
    int tid = threadIdx.x, c = blockIdx.x;
    for (int i = tid; i < NBINS_TOT; i += 1024) {
        lcnt[i] = 0;
        lbase[i] = bin_start[i] + off_rel[c * NBINS_TOT + i];
    }
    __syncthreads();
    int per = (E + NCHUNK - 1) / NCHUNK;
    int e0 = c * per, e1 = min(E, e0 + per);
    for (int e = e0 + tid; e < e1; e += 1024) {
        unsigned int k = keys[e];
        int b = bins[e];
        int pos = lbase[b] + atomicAdd(&lcnt[b], 1);
        sorted1[pos] = k;
    }
}

// ---------------- pass 2: per-(w,bin) LDS counting sort -> window CSR -------
__global__ __launch_bounds__(512) void dlsort_kernel(
    const unsigned int* __restrict__ sorted1,
    const int* __restrict__ bin_start,
    unsigned int* __restrict__ sorted2,
    int* __restrict__ rp, int N) {
    __shared__ int hist[512];
    __shared__ int pfx[512];
    __shared__ int offc[512];
    __shared__ unsigned int stage[CAP];
    int tid = threadIdx.x, b = blockIdx.x;
    int w = b / NBIN_D, dbin = b - w * NBIN_D;
    int bs = bin_start[b], be = bin_start[b + 1];
    int cnt = be - bs;
    hist[tid] = 0;
    __syncthreads();
    for (int e = bs + tid; e < be; e += 512)
        atomicAdd(&hist[(sorted1[e] >> 17) & 511], 1);
    __syncthreads();
    pfx[tid] = hist[tid];
    __syncthreads();
    for (int off = 1; off < 512; off <<= 1) {
        int v = (tid >= off) ? pfx[tid - off] : 0;
        __syncthreads();
        pfx[tid] += v;
        __syncthreads();
    }
    {
        int excl = pfx[tid] - hist[tid];
        offc[tid] = excl;
        int node = dbin * 512 + tid;
        if (node <= N) rp[w * (N + 1) + node] = bs + excl;
    }
    __syncthreads();
    if (cnt <= CAP) {
        for (int e = bs + tid; e < be; e += 512) {
            unsigned int wd = sorted1[e];
            int pos = atomicAdd(&offc[(wd >> 17) & 511], 1);
            stage[pos] = wd;
        }
        __syncthreads();
        for (int i = tid; i < cnt; i += 512) sorted2[bs + i] = stage[i];
    } else {
        for (int e = bs + tid; e < be; e += 512) {
            unsigned int wd = sorted1[e];
            int pos = bs + atomicAdd(&offc[(wd >> 17) & 511], 1);
            sorted2[pos] = wd;
        }
    }
}

// ------- aggregation F=5 (layer 1): 4 lanes/node (edge 4-split), serial w ---
__global__ __launch_bounds__(256) void agg5_csr(
    const unsigned int* __restrict__ sorted2, const int* __restrict__ rp,
    const float4* __restrict__ xp, float* __restrict__ agg, int N) {
    int t = blockIdx.x * 256 + threadIdx.x;
    int n = t >> 2, p = t & 3;
    if (n >= N) return;
    float a0 = 0, a1 = 0, a2 = 0, a3 = 0, a4 = 0;
#pragma unroll
    for (int w = 0; w < NW; ++w) {
        int e0 = rp[w * (N + 1) + n], e1 = rp[w * (N + 1) + n + 1];
        int e = e0 + p;
        for (; e + 4 < e1; e += 8) {
            int s0 = (int)(sorted2[e] & 0x1FFFF);
            int s1 = (int)(sorted2[e + 4] & 0x1FFFF);
            float4 v0 = xp[s0 * 2], w0 = xp[s0 * 2 + 1];
            float4 v1 = xp[s1 * 2], w1 = xp[s1 * 2 + 1];
            a0 += v0.x; a1 += v0.y; a2 += v0.z; a3 += v0.w; a4 += w0.x;
            a0 += v1.x; a1 += v1.y; a2 += v1.z; a3 += v1.w; a4 += w1.x;
        }
        for (; e < e1; e += 4) {
            int s0 = (int)(sorted2[e] & 0x1FFFF);
            float4 v0 = xp[s0 * 2], w0 = xp[s0 * 2 + 1];
            a0 += v0.x; a1 += v0.y; a2 += v0.z; a3 += v0.w; a4 += w0.x;
        }
    }
    // combine the four edge-split lanes
    a0 += __shfl_xor(a0, 1); a1 += __shfl_xor(a1, 1); a2 += __shfl_xor(a2, 1);
    a3 += __shfl_xor(a3, 1); a4 += __shfl_xor(a4, 1);
    a0 += __shfl_xor(a0, 2); a1 += __shfl_xor(a1, 2); a2 += __shfl_xor(a2, 2);
    a3 += __shfl_xor(a3, 2); a4 += __shfl_xor(a4, 2);
    if (p == 0) {
        float* o = agg + (long long)n * 5;
        o[0] = a0; o[1] = a1; o[2] = a2; o[3] = a3; o[4] = a4;
    }
}

// -- aggregation F=16 (layer 2): 16 lanes/node (quad x 4-way edge), serial w -
// q = feature quad (contiguous 64B line across q=0..3), p = edge 4-split.
// Windows remain SERIAL per thread (machine-wide window sweep -> L2-resident).
__global__ __launch_bounds__(256) void agg16_csr(
    const unsigned int* __restrict__ sorted2, const int* __restrict__ rp,
    const float4* __restrict__ h, float* __restrict__ agg, int N) {
    int t = blockIdx.x * 256 + threadIdx.x;
    int n = t >> 4, l = t & 15;
    int q = l & 3, p = l >> 2;     // p in 0..3
    if (n >= N) return;
    float a0 = 0, a1 = 0, a2 = 0, a3 = 0;
#pragma unroll
    for (int w = 0; w < NW; ++w) {
        int e0 = rp[w * (N + 1) + n], e1 = rp[w * (N + 1) + n + 1];
        int e = e0 + p;
        for (; e + 4 < e1; e += 8) {
            int s0 = (int)(sorted2[e] & 0x1FFFF);
            int s1 = (int)(sorted2[e + 4] & 0x1FFFF);
            float4 v0 = h[s0 * 4 + q];
            float4 v1 = h[s1 * 4 + q];
            a0 += v0.x; a1 += v0.y; a2 += v0.z; a3 += v0.w;
            a0 += v1.x; a1 += v1.y; a2 += v1.z; a3 += v1.w;
        }
        for (; e < e1; e += 4) {
            int s0 = (int)(sorted2[e] & 0x1FFFF);
            float4 v0 = h[s0 * 4 + q];
            a0 += v0.x; a1 += v0.y; a2 += v0.z; a3 += v0.w;
        }
    }
    // combine the four edge-split groups (lanes l, l^4, l^8, l^12)
    a0 += __shfl_xor(a0, 4); a1 += __shfl_xor(a1, 4);
    a2 += __shfl_xor(a2, 4); a3 += __shfl_xor(a3, 4);
    a0 += __shfl_xor(a0, 8); a1 += __shfl_xor(a1, 8);
    a2 += __shfl_xor(a2, 8); a3 += __shfl_xor(a3, 8);
    if (p == 0) {
        float4* o = (float4*)(agg + (long long)n * 16);
        o[q] = make_float4(a0, a1, a2, a3);
    }
}

// ------------- MLP1: h = relu((x+agg1)@W1a+b1a)@W1b+b1b  (fp32 h) -----------
__global__ void mlp1_kernel(const float* __restrict__ x,
                            const float* __restrict__ agg,
                            const float* __restrict__ W1, const float* __restrict__ b1,
                            const float* __restrict__ W2, const float* __restrict__ b2,
                            float* __restrict__ h, int N) {
    int n = blockIdx.x * blockDim.x + threadIdx.x;
    if (n >= N) return;
    float in[5];
#pragma unroll
    for (int f = 0; f < 5; ++f)
        in[f] = x[(long long)n * 5 + f] + agg[(long long)n * 5 + f];
    float hid[16];
#pragma unroll
    for (int j = 0; j < 16; ++j) {
        float acc = b1[j];
#pragma unroll
        for (int f = 0; f < 5; ++f) acc = fmaf(in[f], W1[f * 16 + j], acc);
        hid[j] = fmaxf(acc, 0.0f);
    }
    float4* op = (float4*)(h + (long long)n * 16);
#pragma unroll
    for (int jq = 0; jq < 4; ++jq) {
        float4 v;
        float acc;
        acc = b2[jq * 4 + 0];
#pragma unroll
        for (int k = 0; k < 16; ++k) acc = fmaf(hid[k], W2[k * 16 + jq * 4 + 0], acc);
        v.x = acc;
        acc = b2[jq * 4 + 1];
#pragma unroll
        for (int k = 0; k < 16; ++k) acc = fmaf(hid[k], W2[k * 16 + jq * 4 + 1], acc);
        v.y = acc;
        acc = b2[jq * 4 + 2];
#pragma unroll
        for (int k = 0; k < 16; ++k) acc = fmaf(hid[k], W2[k * 16 + jq * 4 + 2], acc);
        v.z = acc;
        acc = b2[jq * 4 + 3];
#pragma unroll
        for (int k = 0; k < 16; ++k) acc = fmaf(hid[k], W2[k * 16 + jq * 4 + 3], acc);
        v.w = acc;
        op[jq] = v;
    }
}

// ------------- MLP2: out = relu((h+agg2)@W2a+b2a)@W2b+b2b -------------------
__global__ void mlp2_kernel(const float* __restrict__ h,
                            const float* __restrict__ agg,
                            const float* __restrict__ W1, const float* __restrict__ b1,
                            const float* __restrict__ W2, const float* __restrict__ b2,
                            float* __restrict__ out, int N) {
    int n = blockIdx.x * blockDim.x + threadIdx.x;
    if (n >= N) return;
    float in[16];
    const float4* hp = (const float4*)(h + (long long)n * 16);
    const float4* ap = (const float4*)(agg + (long long)n * 16);
#pragma unroll
    for (int qq = 0; qq < 4; ++qq) {
        float4 a = hp[qq], b = ap[qq];
        in[qq * 4 + 0] = a.x + b.x; in[qq * 4 + 1] = a.y + b.y;
        in[qq * 4 + 2] = a.z + b.z; in[qq * 4 + 3] = a.w + b.w;
    }
    float hid[16];
#pragma unroll
    for (int j = 0; j < 16; ++j) {
        float acc = b1[j];
#pragma unroll
        for (int f = 0; f < 16; ++f) acc = fmaf(in[f], W1[f * 16 + j], acc);
        hid[j] = fmaxf(acc, 0.0f);
    }
    float4* op = (float4*)(out + (long long)n * 16);
#pragma unroll
    for (int jq = 0; jq < 4; ++jq) {
        float4 v;
        float acc;
        acc = b2[jq * 4 + 0];
#pragma unroll
        for (int k = 0; k < 16; ++k) acc = fmaf(hid[k], W2[k * 16 + jq * 4 + 0], acc);
        v.x = acc;
        acc = b2[jq * 4 + 1];
#pragma unroll
        for (int k = 0; k < 16; ++k) acc = fmaf(hid[k], W2[k * 16 + jq * 4 + 1], acc);
        v.y = acc;
        acc = b2[jq * 4 + 2];
#pragma unroll
        for (int k = 0; k < 16; ++k) acc = fmaf(hid[k], W2[k * 16 + jq * 4 + 2], acc);
        v.z = acc;
        acc = b2[jq * 4 + 3];
#pragma unroll
        for (int k = 0; k < 16; ++k) acc = fmaf(hid[k], W2[k * 16 + jq * 4 + 3], acc);
        v.w = acc;
        op[jq] = v;
    }
}

// ---------- fallback path (ws too small): global atomics, fp32 --------------
__device__ __forceinline__ void load_edge(const void* eidx, unsigned int is32,
                                          int i, int E, int& s, int& d) {
    if (is32 == 0u) {
        const long long* p = (const long long*)eidx;
        s = (int)p[i]; d = (int)p[E + i];
    } else {
        const int* p = (const int*)eidx;
        s = p[i]; d = p[E + i];
    }
}

__global__ void scatter_f5_kernel(const void* __restrict__ eidx,
                                  const unsigned int* __restrict__ flag,
                                  const float* __restrict__ x,
                                  float* __restrict__ agg, int E) {
    int i = blockIdx.x * blockDim.x + threadIdx.x;
    if (i >= E) return;
    int s, d; load_edge(eidx, *flag, i, E, s, d);
    const float* xs = x + (long long)s * 5;
    float* a = agg + (long long)d * 5;
#pragma unroll
    for (int f = 0; f < 5; ++f) atomicAdd(&a[f], xs[f]);
}

__global__ void scatter_f16_kernel(const void* __restrict__ eidx,
                                   const unsigned int* __restrict__ flag,
                                   const float* __restrict__ h,
                                   float* __restrict__ agg, int E) {
    int i = blockIdx.x * blockDim.x + threadIdx.x;
    if (i >= E) return;
    int s, d; load_edge(eidx, *flag, i, E, s, d);
    const float* hs = h + (long long)s * 16;
    float* a = agg + (long long)d * 16;
#pragma unroll
    for (int f = 0; f < 16; ++f) atomicAdd(&a[f], hs[f]);
}

extern "C" void kernel_launch(void* const* d_in, const int* in_sizes, int n_in,
                              void* d_out, int out_size, void* d_ws, size_t ws_size,
                              hipStream_t stream) {
    const float* x    = (const float*)d_in[0];
    const void*  eidx = d_in[1];
    const float* W1a  = (const float*)d_in[2];
    const float* b1a  = (const float*)d_in[3];
    const float* W1b  = (const float*)d_in[4];
    const float* b1b  = (const float*)d_in[5];
    const float* W2a  = (const float*)d_in[6];
    const float* b2a  = (const float*)d_in[7];
    const float* W2b  = (const float*)d_in[8];
    const float* b2b  = (const float*)d_in[9];
    float* out = (float*)d_out;

    const int E = in_sizes[1] / 2;
    const int N = N_NODES;

    char* ws = (char*)d_ws;
    auto align256 = [](size_t v) { return (v + 255) & ~(size_t)255; };
    const size_t hist_bytes = (size_t)NCHUNK * NBINS_TOT * 4;          // 802,816

    const size_t off_flag     = 0;
    const size_t off_binstart = 256;                                    // 785*4
    const size_t off_totals   = align256(off_binstart + (NBINS_TOT + 1) * 4);
    const size_t off_rp       = align256(off_totals + NBINS_TOT * 4);   // NW*(N+1)*4
    const size_t off_hist     = align256(off_rp + (size_t)NW * (N + 1) * 4);
    const size_t off_offrel   = align256(off_hist + hist_bytes);
    const size_t off_xp       = align256(off_offrel + hist_bytes);      // N*32 fp32x8
    const size_t off_sorted1  = align256(off_xp + (size_t)N * 32);      // E*4
    const size_t off_sorted2  = align256(off_sorted1 + (size_t)E * 4);  // E*4 (also keys)
    const size_t off_bins     = align256(off_sorted2 + (size_t)E * 4);  // E*2
    const size_t need         = off_bins + (size_t)E * 2;

    // keys alias the sorted2 slot (keys consumed by scatter1 before dlsort
    // writes sorted2). agg1/agg2/h alias the dead sorted1 region after dlsort:
    //   agg1 @ +0, agg2 @ +2MiB, h @ +9MiB  (15.8 MB < E*4 = 25.6 MB)
    unsigned int* flag = (unsigned int*)(ws + off_flag);

    if (ws_size >= need && (size_t)E * 4 >= 9 * 1024 * 1024 + (size_t)N * 64) {
        int* bin_start        = (int*)(ws + off_binstart);
        int* totals           = (int*)(ws + off_totals);
        int* rp               = (int*)(ws + off_rp);
        int* hist             = (int*)(ws + off_hist);
        int* off_rel          = (int*)(ws + off_offrel);
        float4* xp            = (float4*)(ws + off_xp);
        unsigned int* sorted1 = (unsigned int*)(ws + off_sorted1);
        unsigned int* sorted2 = (unsigned int*)(ws + off_sorted2);
        unsigned int* keys    = (unsigned int*)(ws + off_sorted2);      // alias
        unsigned short* bins  = (unsigned short*)(ws + off_bins);
        float* agg1 = (float*)(ws + off_sorted1);
        float* agg2 = (float*)(ws + off_sorted1 + 2 * 1024 * 1024);
        float* h    = (float*)(ws + off_sorted1 + 9 * 1024 * 1024);

        const int per = (E + NCHUNK - 1) / NCHUNK;

        hipMemsetAsync(ws, 0, 4, stream);
        detect_i64_kernel<<<8, 256, 0, stream>>>((const unsigned int*)eidx, flag);
        pad_x_kernel<<<(N + 255) / 256, 256, 0, stream>>>(x, xp, N);
        count_kernel<<<NCHUNK, 1024, 0, stream>>>(eidx, flag, hist, keys, bins, E);
        scan1_kernel<<<(NBINS_TOT * 64 + 511) / 512, 512, 0, stream>>>(hist, off_rel, totals);
        scan2_kernel<<<1, 1024, 0, stream>>>(totals, bin_start);
        if (per <= CHUNK_CAP) {
            scatter1_staged<<<NCHUNK, 1024, 0, stream>>>(keys, bins, hist, off_rel,
                                                         bin_start, sorted1, E);
        } else {
            scatter1_kernel<<<NCHUNK, 1024, 0, stream>>>(keys, bins, off_rel,
                                                         bin_start, sorted1, E);
        }
        dlsort_kernel<<<NBINS_TOT, 512, 0, stream>>>(sorted1, bin_start, sorted2, rp, N);

        agg5_csr<<<(4 * N + 255) / 256, 256, 0, stream>>>(sorted2, rp, xp, agg1, N);
        mlp1_kernel<<<(N + 255) / 256, 256, 0, stream>>>(x, agg1, W1a, b1a, W1b, b1b, h, N);
        agg16_csr<<<(16 * N + 255) / 256, 256, 0, stream>>>(sorted2, rp, (const float4*)h, agg2, N);
        mlp2_kernel<<<(N + 255) / 256, 256, 0, stream>>>(h, agg2, W2a, b2a, W2b, b2b, out, N);
    } else {
        // fallback: global-atomic path
        const size_t f_agg1 = 4096;
        const size_t f_agg2 = f_agg1 + 2 * 1024 * 1024;
        const size_t f_h    = f_agg2 + 7 * 1024 * 1024;
        float* agg1 = (float*)(ws + f_agg1);
        float* agg2 = (float*)(ws + f_agg2);
        float* h    = (float*)(ws + f_h);

        hipMemsetAsync(ws, 0, f_agg2 + (size_t)N * 16 * 4, stream);
        detect_i64_kernel<<<8, 256, 0, stream>>>((const unsigned int*)eidx, flag);
        int blocks = (E + 255) / 256;
        scatter_f5_kernel<<<blocks, 256, 0, stream>>>(eidx, flag, x, agg1, E);
        mlp1_kernel<<<(N + 255) / 256, 256, 0, stream>>>(x, agg1, W1a, b1a, W1b, b1b, h, N);
        scatter_f16_kernel<<<blocks, 256, 0, stream>>>(eidx, flag, h, agg2, E);
        mlp2_kernel<<<(N + 255) / 256, 256, 0, stream>>>(h, agg2, W2a, b2a, W2b, b2b, out, N);
    }
}

// Round 19
// 189.162 us; speedup vs baseline: 1.0915x; 1.0364x over previous
//
#include <hip/hip_runtime.h>

#define N_NODES 100000
#define NBIN_D  196           // dst bins of 512 nodes (196*512 = 100352)
#define NW      4             // src windows of 25000 nodes (uniform)
#define WSPAN   25000
#define NBINS_TOT (NW * NBIN_D)   // 784 sort bins, w-major
#define NCHUNK  256
#define CAP     12032         // dlsort LDS stage (mean bin = 8163, +43 sigma)
#define CHUNK_CAP 26624       // scatter1 LDS stage (chunk = 25000 edges)

// ---------------- dtype detection (int64 vs int32 edge_index) ---------------
__global__ void detect_i64_kernel(const unsigned int* __restrict__ e,
                                  unsigned int* __restrict__ flag) {
    int i = blockIdx.x * blockDim.x + threadIdx.x;  // 0..2047
    unsigned int v = e[2 * i + 1];
    if (v != 0u) atomicOr(flag, 1u);
}

// ---------------- pad x (N x 5 f32) -> fp32x8 (32B rows) --------------------
__global__ void pad_x_kernel(const float* __restrict__ x, float4* __restrict__ xp, int N) {
    int n = blockIdx.x * blockDim.x + threadIdx.x;
    if (n >= N) return;
    const float* p = x + (long long)n * 5;
    xp[n * 2]     = make_float4(p[0], p[1], p[2], p[3]);
    xp[n * 2 + 1] = make_float4(p[4], 0.f, 0.f, 0.f);
}

// ------- pass 1a: histogram over (w, dst_bin) + emit compact key stream -----
// keys[e] = (dl<<17)|src, bins[e] = sort-bin index (w*NBIN_D + dbin)
__global__ __launch_bounds__(1024) void count_kernel(
    const void* __restrict__ eidx, const unsigned int* __restrict__ flag,
    int* __restrict__ hist, unsigned int* __restrict__ keys,
    unsigned short* __restrict__ bins, int E) {
    __shared__ int lh[NBINS_TOT];
    int tid = threadIdx.x, c = blockIdx.x;
    for (int i = tid; i < NBINS_TOT; i += 1024) lh[i] = 0;
    __syncthreads();
    int per = (E + NCHUNK - 1) / NCHUNK;
    int e0 = c * per, e1 = min(E, e0 + per);
    unsigned int is32 = *flag;
    for (int e = e0 + tid; e < e1; e += 1024) {
        int s, d;
        if (is32) {
            const int* p = (const int*)eidx; s = p[e]; d = p[E + e];
        } else {
            const long long* p = (const long long*)eidx; s = (int)p[e]; d = (int)p[E + e];
        }
        int b = (s / WSPAN) * NBIN_D + (d >> 9);
        keys[e] = ((unsigned int)(d & 511) << 17) | (unsigned int)s;
        bins[e] = (unsigned short)b;
        atomicAdd(&lh[b], 1);
    }
    __syncthreads();
    for (int i = tid; i < NBINS_TOT; i += 1024) hist[c * NBINS_TOT + i] = lh[i];
}

// ---------------- pass 1b: per-bin column scan (1 wave per bin) -------------
__global__ void scan1_kernel(const int* __restrict__ hist,
                             int* __restrict__ off_rel,
                             int* __restrict__ totals) {
    int gtid = blockIdx.x * blockDim.x + threadIdx.x;
    int b = gtid >> 6;
    int lane = threadIdx.x & 63;
    if (b >= NBINS_TOT) return;
    int carry = 0;
    for (int k = 0; k < NCHUNK; k += 64) {
        int v = hist[(k + lane) * NBINS_TOT + b];
        int sc = v;
        for (int off = 1; off < 64; off <<= 1) {
            int t = __shfl_up(sc, off);
            if (lane >= off) sc += t;
        }
        off_rel[(k + lane) * NBINS_TOT + b] = carry + sc - v;   // exclusive
        carry += __shfl(sc, 63);
    }
    if (lane == 0) totals[b] = carry;
}

// ---------------- pass 1c: scan bin totals -> bin_start ---------------------
__global__ void scan2_kernel(const int* __restrict__ totals,
                             int* __restrict__ bin_start) {
    __shared__ int buf[1024];
    int tid = threadIdx.x;
    buf[tid] = (tid < NBINS_TOT) ? totals[tid] : 0;
    __syncthreads();
    for (int off = 1; off < 1024; off <<= 1) {
        int v = (tid >= off) ? buf[tid - off] : 0;
        __syncthreads();
        buf[tid] += v;
        __syncthreads();
    }
    if (tid < NBINS_TOT) bin_start[tid + 1] = buf[tid];
    if (tid == 0) bin_start[0] = 0;
}

// ------- pass 1d: LDS counting sort per chunk -> coalesced global writes ----
__global__ __launch_bounds__(1024) void scatter1_staged(
    const unsigned int* __restrict__ keys, const unsigned short* __restrict__ bins,
    const int* __restrict__ hist, const int* __restrict__ off_rel,
    const int* __restrict__ bin_start,
    unsigned int* __restrict__ sorted1, int E) {
    __shared__ unsigned int staged[CHUNK_CAP];
    __shared__ int lstart[NBINS_TOT];
    __shared__ int lcur[NBINS_TOT];
    __shared__ int scanbuf[1024];
    int tid = threadIdx.x, c = blockIdx.x;
    int v = (tid < NBINS_TOT) ? hist[c * NBINS_TOT + tid] : 0;
    scanbuf[tid] = v;
    __syncthreads();
    for (int off = 1; off < 1024; off <<= 1) {
        int t = (tid >= off) ? scanbuf[tid - off] : 0;
        __syncthreads();
        scanbuf[tid] += t;
        __syncthreads();
    }
    if (tid < NBINS_TOT) {
        int excl = scanbuf[tid] - v;
        lstart[tid] = excl;
        lcur[tid] = excl;
    }
    __syncthreads();
    int per = (E + NCHUNK - 1) / NCHUNK;
    int e0 = c * per, e1 = min(E, e0 + per);
    for (int e = e0 + tid; e < e1; e += 1024) {
        unsigned int k = keys[e];
        int b = bins[e];
        int pos = atomicAdd(&lcur[b], 1);
        staged[pos] = k;
    }
    __syncthreads();
    int wv = tid >> 6, lane = tid & 63;
    for (int b = wv; b < NBINS_TOT; b += 16) {
        int ls = lstart[b];
        int cnt = lcur[b] - ls;
        int gd = bin_start[b] + off_rel[c * NBINS_TOT + b];
        for (int i = lane; i < cnt; i += 64)
            sorted1[gd + i] = staged[ls + i];
    }
}

// ---- fallback scatter (per > CHUNK_CAP): scattered stores, always correct --
__global__ __launch_bounds__(1024) void scatter1_kernel(
    const unsigned int* __restrict__ keys, const unsigned short* __restrict__ bins,
    const int* __restrict__ off_rel, const int* __restrict__ bin_start,
    unsigned int* __restrict__ sorted1, int E) {
    __shared__ int lcnt[NBINS_TOT];
    __shared__ int lbase[NBINS_TOT];
    int tid = threadIdx.x, c = blockIdx.x;
    for (int i = tid; i < NBINS_TOT; i += 1024) {
        lcnt[i] = 0;
        lbase[i] = bin_start[i] + off_rel[c * NBINS_TOT + i];
    }
    __syncthreads();
    int per = (E + NCHUNK - 1) / NCHUNK;
    int e0 = c * per, e1 = min(E, e0 + per);
    for (int e = e0 + tid; e < e1; e += 1024) {
        unsigned int k = keys[e];
        int b = bins[e];
        int pos = lbase[b] + atomicAdd(&lcnt[b], 1);
        sorted1[pos] = k;
    }
}

// ---------------- pass 2: per-(w,bin) LDS counting sort -> window CSR -------
__global__ __launch_bounds__(512) void dlsort_kernel(
    const unsigned int* __restrict__ sorted1,
    const int* __restrict__ bin_start,
    unsigned int* __restrict__ sorted2,
    int* __restrict__ rp, int N) {
    __shared__ int hist[512];
    __shared__ int pfx[512];
    __shared__ int offc[512];
    __shared__ unsigned int stage[CAP];
    int tid = threadIdx.x, b = blockIdx.x;
    int w = b / NBIN_D, dbin = b - w * NBIN_D;
    int bs = bin_start[b], be = bin_start[b + 1];
    int cnt = be - bs;
    hist[tid] = 0;
    __syncthreads();
    for (int e = bs + tid; e < be; e += 512)
        atomicAdd(&hist[(sorted1[e] >> 17) & 511], 1);
    __syncthreads();
    pfx[tid] = hist[tid];
    __syncthreads();
    for (int off = 1; off < 512; off <<= 1) {
        int v = (tid >= off) ? pfx[tid - off] : 0;
        __syncthreads();
        pfx[tid] += v;
        __syncthreads();
    }
    {
        int excl = pfx[tid] - hist[tid];
        offc[tid] = excl;
        int node = dbin * 512 + tid;
        if (node <= N) rp[w * (N + 1) + node] = bs + excl;
    }
    __syncthreads();
    if (cnt <= CAP) {
        for (int e = bs + tid; e < be; e += 512) {
            unsigned int wd = sorted1[e];
            int pos = atomicAdd(&offc[(wd >> 17) & 511], 1);
            stage[pos] = wd;
        }
        __syncthreads();
        for (int i = tid; i < cnt; i += 512) sorted2[bs + i] = stage[i];
    } else {
        for (int e = bs + tid; e < be; e += 512) {
            unsigned int wd = sorted1[e];
            int pos = bs + atomicAdd(&offc[(wd >> 17) & 511], 1);
            sorted2[pos] = wd;
        }
    }
}

// ------- aggregation F=5 (layer 1): 4 lanes/node (edge 4-split), serial w ---
__global__ __launch_bounds__(256) void agg5_csr(
    const unsigned int* __restrict__ sorted2, const int* __restrict__ rp,
    const float4* __restrict__ xp, float* __restrict__ agg, int N) {
    int t = blockIdx.x * 256 + threadIdx.x;
    int n = t >> 2, p = t & 3;
    if (n >= N) return;
    float a0 = 0, a1 = 0, a2 = 0, a3 = 0, a4 = 0;
#pragma unroll
    for (int w = 0; w < NW; ++w) {
        int e0 = rp[w * (N + 1) + n], e1 = rp[w * (N + 1) + n + 1];
        int e = e0 + p;
        for (; e + 4 < e1; e += 8) {
            int s0 = (int)(sorted2[e] & 0x1FFFF);
            int s1 = (int)(sorted2[e + 4] & 0x1FFFF);
            float4 v0 = xp[s0 * 2], w0 = xp[s0 * 2 + 1];
            float4 v1 = xp[s1 * 2], w1 = xp[s1 * 2 + 1];
            a0 += v0.x; a1 += v0.y; a2 += v0.z; a3 += v0.w; a4 += w0.x;
            a0 += v1.x; a1 += v1.y; a2 += v1.z; a3 += v1.w; a4 += w1.x;
        }
        for (; e < e1; e += 4) {
            int s0 = (int)(sorted2[e] & 0x1FFFF);
            float4 v0 = xp[s0 * 2], w0 = xp[s0 * 2 + 1];
            a0 += v0.x; a1 += v0.y; a2 += v0.z; a3 += v0.w; a4 += w0.x;
        }
    }
    // combine the four edge-split lanes
    a0 += __shfl_xor(a0, 1); a1 += __shfl_xor(a1, 1); a2 += __shfl_xor(a2, 1);
    a3 += __shfl_xor(a3, 1); a4 += __shfl_xor(a4, 1);
    a0 += __shfl_xor(a0, 2); a1 += __shfl_xor(a1, 2); a2 += __shfl_xor(a2, 2);
    a3 += __shfl_xor(a3, 2); a4 += __shfl_xor(a4, 2);
    if (p == 0) {
        float* o = agg + (long long)n * 5;
        o[0] = a0; o[1] = a1; o[2] = a2; o[3] = a3; o[4] = a4;
    }
}

// -- aggregation F=16 (layer 2): 8 lanes/node (quad x edge-parity), serial w -
// q = feature quad (contiguous 64B line across q=0..3), p = edge parity.
__global__ __launch_bounds__(256) void agg16_csr(
    const unsigned int* __restrict__ sorted2, const int* __restrict__ rp,
    const float4* __restrict__ h, float* __restrict__ agg, int N) {
    int t = blockIdx.x * 256 + threadIdx.x;
    int n = t >> 3, l = t & 7;
    int q = l & 3, p = l >> 2;
    if (n >= N) return;
    float a0 = 0, a1 = 0, a2 = 0, a3 = 0;
#pragma unroll
    for (int w = 0; w < NW; ++w) {
        int e0 = rp[w * (N + 1) + n], e1 = rp[w * (N + 1) + n + 1];
        int e = e0 + p;
        for (; e + 6 < e1; e += 8) {
            int s0 = (int)(sorted2[e] & 0x1FFFF);
            int s1 = (int)(sorted2[e + 2] & 0x1FFFF);
            int s2 = (int)(sorted2[e + 4] & 0x1FFFF);
            int s3 = (int)(sorted2[e + 6] & 0x1FFFF);
            float4 v0 = h[s0 * 4 + q];
            float4 v1 = h[s1 * 4 + q];
            float4 v2 = h[s2 * 4 + q];
            float4 v3 = h[s3 * 4 + q];
            a0 += v0.x; a1 += v0.y; a2 += v0.z; a3 += v0.w;
            a0 += v1.x; a1 += v1.y; a2 += v1.z; a3 += v1.w;
            a0 += v2.x; a1 += v2.y; a2 += v2.z; a3 += v2.w;
            a0 += v3.x; a1 += v3.y; a2 += v3.z; a3 += v3.w;
        }
        for (; e < e1; e += 2) {
            int s0 = (int)(sorted2[e] & 0x1FFFF);
            float4 v0 = h[s0 * 4 + q];
            a0 += v0.x; a1 += v0.y; a2 += v0.z; a3 += v0.w;
        }
    }
    // combine the two edge-parity halves (lane l <-> l^4)
    a0 += __shfl_xor(a0, 4);
    a1 += __shfl_xor(a1, 4);
    a2 += __shfl_xor(a2, 4);
    a3 += __shfl_xor(a3, 4);
    if (p == 0) {
        float4* o = (float4*)(agg + (long long)n * 16);
        o[q] = make_float4(a0, a1, a2, a3);
    }
}

// ------------- MLP1: h = relu((x+agg1)@W1a+b1a)@W1b+b1b  (fp32 h) -----------
__global__ void mlp1_kernel(const float* __restrict__ x,
                            const float* __restrict__ agg,
                            const float* __restrict__ W1, const float* __restrict__ b1,
                            const float* __restrict__ W2, const float* __restrict__ b2,
                            float* __restrict__ h, int N) {
    int n = blockIdx.x * blockDim.x + threadIdx.x;
    if (n >= N) return;
    float in[5];
#pragma unroll
    for (int f = 0; f < 5; ++f)
        in[f] = x[(long long)n * 5 + f] + agg[(long long)n * 5 + f];
    float hid[16];
#pragma unroll
    for (int j = 0; j < 16; ++j) {
        float acc = b1[j];
#pragma unroll
        for (int f = 0; f < 5; ++f) acc = fmaf(in[f], W1[f * 16 + j], acc);
        hid[j] = fmaxf(acc, 0.0f);
    }
    float4* op = (float4*)(h + (long long)n * 16);
#pragma unroll
    for (int jq = 0; jq < 4; ++jq) {
        float4 v;
        float acc;
        acc = b2[jq * 4 + 0];
#pragma unroll
        for (int k = 0; k < 16; ++k) acc = fmaf(hid[k], W2[k * 16 + jq * 4 + 0], acc);
        v.x = acc;
        acc = b2[jq * 4 + 1];
#pragma unroll
        for (int k = 0; k < 16; ++k) acc = fmaf(hid[k], W2[k * 16 + jq * 4 + 1], acc);
        v.y = acc;
        acc = b2[jq * 4 + 2];
#pragma unroll
        for (int k = 0; k < 16; ++k) acc = fmaf(hid[k], W2[k * 16 + jq * 4 + 2], acc);
        v.z = acc;
        acc = b2[jq * 4 + 3];
#pragma unroll
        for (int k = 0; k < 16; ++k) acc = fmaf(hid[k], W2[k * 16 + jq * 4 + 3], acc);
        v.w = acc;
        op[jq] = v;
    }
}

// ------------- MLP2: out = relu((h+agg2)@W2a+b2a)@W2b+b2b -------------------
__global__ void mlp2_kernel(const float* __restrict__ h,
                            const float* __restrict__ agg,
                            const float* __restrict__ W1, const float* __restrict__ b1,
                            const float* __restrict__ W2, const float* __restrict__ b2,
                            float* __restrict__ out, int N) {
    int n = blockIdx.x * blockDim.x + threadIdx.x;
    if (n >= N) return;
    float in[16];
    const float4* hp = (const float4*)(h + (long long)n * 16);
    const float4* ap = (const float4*)(agg + (long long)n * 16);
#pragma unroll
    for (int qq = 0; qq < 4; ++qq) {
        float4 a = hp[qq], b = ap[qq];
        in[qq * 4 + 0] = a.x + b.x; in[qq * 4 + 1] = a.y + b.y;
        in[qq * 4 + 2] = a.z + b.z; in[qq * 4 + 3] = a.w + b.w;
    }
    float hid[16];
#pragma unroll
    for (int j = 0; j < 16; ++j) {
        float acc = b1[j];
#pragma unroll
        for (int f = 0; f < 16; ++f) acc = fmaf(in[f], W1[f * 16 + j], acc);
        hid[j] = fmaxf(acc, 0.0f);
    }
    float4* op = (float4*)(out + (long long)n * 16);
#pragma unroll
    for (int jq = 0; jq < 4; ++jq) {
        float4 v;
        float acc;
        acc = b2[jq * 4 + 0];
#pragma unroll
        for (int k = 0; k < 16; ++k) acc = fmaf(hid[k], W2[k * 16 + jq * 4 + 0], acc);
        v.x = acc;
        acc = b2[jq * 4 + 1];
#pragma unroll
        for (int k = 0; k < 16; ++k) acc = fmaf(hid[k], W2[k * 16 + jq * 4 + 1], acc);
        v.y = acc;
        acc = b2[jq * 4 + 2];
#pragma unroll
        for (int k = 0; k < 16; ++k) acc = fmaf(hid[k], W2[k * 16 + jq * 4 + 2], acc);
        v.z = acc;
        acc = b2[jq * 4 + 3];
#pragma unroll
        for (int k = 0; k < 16; ++k) acc = fmaf(hid[k], W2[k * 16 + jq * 4 + 3], acc);
        v.w = acc;
        op[jq] = v;
    }
}

// ---------- fallback path (ws too small): global atomics, fp32 --------------
__device__ __forceinline__ void load_edge(const void* eidx, unsigned int is32,
                                          int i, int E, int& s, int& d) {
    if (is32 == 0u) {
        const long long* p = (const long long*)eidx;
        s = (int)p[i]; d = (int)p[E + i];
    } else {
        const int* p = (const int*)eidx;
        s = p[i]; d = p[E + i];
    }
}

__global__ void scatter_f5_kernel(const void* __restrict__ eidx,
                                  const unsigned int* __restrict__ flag,
                                  const float* __restrict__ x,
                                  float* __restrict__ agg, int E) {
    int i = blockIdx.x * blockDim.x + threadIdx.x;
    if (i >= E) return;
    int s, d; load_edge(eidx, *flag, i, E, s, d);
    const float* xs = x + (long long)s * 5;
    float* a = agg + (long long)d * 5;
#pragma unroll
    for (int f = 0; f < 5; ++f) atomicAdd(&a[f], xs[f]);
}

__global__ void scatter_f16_kernel(const void* __restrict__ eidx,
                                   const unsigned int* __restrict__ flag,
                                   const float* __restrict__ h,
                                   float* __restrict__ agg, int E) {
    int i = blockIdx.x * blockDim.x + threadIdx.x;
    if (i >= E) return;
    int s, d; load_edge(eidx, *flag, i, E, s, d);
    const float* hs = h + (long long)s * 16;
    float* a = agg + (long long)d * 16;
#pragma unroll
    for (int f = 0; f < 16; ++f) atomicAdd(&a[f], hs[f]);
}

extern "C" void kernel_launch(void* const* d_in, const int* in_sizes, int n_in,
                              void* d_out, int out_size, void* d_ws, size_t ws_size,
                              hipStream_t stream) {
    const float* x    = (const float*)d_in[0];
    const void*  eidx = d_in[1];
    const float* W1a  = (const float*)d_in[2];
    const float* b1a  = (const float*)d_in[3];
    const float* W1b  = (const float*)d_in[4];
    const float* b1b  = (const float*)d_in[5];
    const float* W2a  = (const float*)d_in[6];
    const float* b2a  = (const float*)d_in[7];
    const float* W2b  = (const float*)d_in[8];
    const float* b2b  = (const float*)d_in[9];
    float* out = (float*)d_out;

    const int E = in_sizes[1] / 2;
    const int N = N_NODES;

    char* ws = (char*)d_ws;
    auto align256 = [](size_t v) { return (v + 255) & ~(size_t)255; };
    const size_t hist_bytes = (size_t)NCHUNK * NBINS_TOT * 4;          // 802,816

    const size_t off_flag     = 0;
    const size_t off_binstart = 256;                                    // 785*4
    const size_t off_totals   = align256(off_binstart + (NBINS_TOT + 1) * 4);
    const size_t off_rp       = align256(off_totals + NBINS_TOT * 4);   // NW*(N+1)*4
    const size_t off_hist     = align256(off_rp + (size_t)NW * (N + 1) * 4);
    const size_t off_offrel   = align256(off_hist + hist_bytes);
    const size_t off_xp       = align256(off_offrel + hist_bytes);      // N*32 fp32x8
    const size_t off_sorted1  = align256(off_xp + (size_t)N * 32);      // E*4
    const size_t off_sorted2  = align256(off_sorted1 + (size_t)E * 4);  // E*4 (also keys)
    const size_t off_bins     = align256(off_sorted2 + (size_t)E * 4);  // E*2
    const size_t need         = off_bins + (size_t)E * 2;

    // keys alias the sorted2 slot (keys consumed by scatter1 before dlsort
    // writes sorted2). agg1/agg2/h alias the dead sorted1 region after dlsort:
    //   agg1 @ +0, agg2 @ +2MiB, h @ +9MiB  (15.8 MB < E*4 = 25.6 MB)
    unsigned int* flag = (unsigned int*)(ws + off_flag);

    if (ws_size >= need && (size_t)E * 4 >= 9 * 1024 * 1024 + (size_t)N * 64) {
        int* bin_start        = (int*)(ws + off_binstart);
        int* totals           = (int*)(ws + off_totals);
        int* rp               = (int*)(ws + off_rp);
        int* hist             = (int*)(ws + off_hist);
        int* off_rel          = (int*)(ws + off_offrel);
        float4* xp            = (float4*)(ws + off_xp);
        unsigned int* sorted1 = (unsigned int*)(ws + off_sorted1);
        unsigned int* sorted2 = (unsigned int*)(ws + off_sorted2);
        unsigned int* keys    = (unsigned int*)(ws + off_sorted2);      // alias
        unsigned short* bins  = (unsigned short*)(ws + off_bins);
        float* agg1 = (float*)(ws + off_sorted1);
        float* agg2 = (float*)(ws + off_sorted1 + 2 * 1024 * 1024);
        float* h    = (float*)(ws + off_sorted1 + 9 * 1024 * 1024);

        const int per = (E + NCHUNK - 1) / NCHUNK;

        hipMemsetAsync(ws, 0, 4, stream);
        detect_i64_kernel<<<8, 256, 0, stream>>>((const unsigned int*)eidx, flag);
        pad_x_kernel<<<(N + 255) / 256, 256, 0, stream>>>(x, xp, N);
        count_kernel<<<NCHUNK, 1024, 0, stream>>>(eidx, flag, hist, keys, bins, E);
        scan1_kernel<<<(NBINS_TOT * 64 + 511) / 512, 512, 0, stream>>>(hist, off_rel, totals);
        scan2_kernel<<<1, 1024, 0, stream>>>(totals, bin_start);
        if (per <= CHUNK_CAP) {
            scatter1_staged<<<NCHUNK, 1024, 0, stream>>>(keys, bins, hist, off_rel,
                                                         bin_start, sorted1, E);
        } else {
            scatter1_kernel<<<NCHUNK, 1024, 0, stream>>>(keys, bins, off_rel,
                                                         bin_start, sorted1, E);
        }
        dlsort_kernel<<<NBINS_TOT, 512, 0, stream>>>(sorted1, bin_start, sorted2, rp, N);

        agg5_csr<<<(4 * N + 255) / 256, 256, 0, stream>>>(sorted2, rp, xp, agg1, N);
        mlp1_kernel<<<(N + 255) / 256, 256, 0, stream>>>(x, agg1, W1a, b1a, W1b, b1b, h, N);
        agg16_csr<<<(8 * N + 255) / 256, 256, 0, stream>>>(sorted2, rp, (const float4*)h, agg2, N);
        mlp2_kernel<<<(N + 255) / 256, 256, 0, stream>>>(h, agg2, W2a, b2a, W2b, b2b, out, N);
    } else {
        // fallback: global-atomic path
        const size_t f_agg1 = 4096;
        const size_t f_agg2 = f_agg1 + 2 * 1024 * 1024;
        const size_t f_h    = f_agg2 + 7 * 1024 * 1024;
        float* agg1 = (float*)(ws + f_agg1);
        float* agg2 = (float*)(ws + f_agg2);
        float* h    = (float*)(ws + f_h);

        hipMemsetAsync(ws, 0, f_agg2 + (size_t)N * 16 * 4, stream);
        detect_i64_kernel<<<8, 256, 0, stream>>>((const unsigned int*)eidx, flag);
        int blocks = (E + 255) / 256;
        scatter_f5_kernel<<<blocks, 256, 0, stream>>>(eidx, flag, x, agg1, E);
        mlp1_kernel<<<(N + 255) / 256, 256, 0, stream>>>(x, agg1, W1a, b1a, W1b, b1b, h, N);
        scatter_f16_kernel<<<blocks, 256, 0, stream>>>(eidx, flag, h, agg2, E);
        mlp2_kernel<<<(N + 255) / 256, 256, 0, stream>>>(h, agg2, W2a, b2a, W2b, b2b, out, N);
    }
}